// Round 13
// baseline (181.513 us; speedup 1.0000x reference)
//
#include <hip/hip_runtime.h>
#include <cstdint>
#include <cstddef>

#define GRES 128   // grid resolution (H = W = L)
#define SC   96    // S*C = 6*16 channels

typedef float v2f __attribute__((ext_vector_type(2)));

// Word-select of cvt_pk_f32_fp8 must be a compile-time constant at sema time.
template<bool HI>
__device__ __forceinline__ v2f cvt2(uint32_t q)
{
    return __builtin_amdgcn_cvt_pk_f32_fp8(q, HI);
}

__device__ __forceinline__ uint32_t u4w(const uint4& q, int c)
{
    return c == 0 ? q.x : c == 1 ? q.y : c == 2 ? q.z : q.w;
}

// ---------------------------------------------------------------------------
// LDS-free transpose/quantize (unchanged from round 11 — measured cheap).
//  A[texel][ch 0..64)   : 64 B records (fp8)
//  B[texel][ch 64..96)  : 32 B records (fp8)
//  L[(p,z)][ch 0..96)   : 128 B padded records (fp8 lines)
// ---------------------------------------------------------------------------
#define NPLANE_T (3 * 12 * GRES * GRES)   // 589824
#define NLINE_T  (3 * 12 * GRES)          // 4608

__global__ __launch_bounds__(256) void tp_split(const float* __restrict__ planes,
                                                const float* __restrict__ lines,
                                                uint8_t* __restrict__ A,
                                                uint8_t* __restrict__ B,
                                                uint8_t* __restrict__ L)
{
    int t = blockIdx.x * 256 + threadIdx.x;
    if (t < NPLANE_T) {
        int xy = t & (GRES * GRES - 1);      // y*128 + x
        int pg = t >> 14;                    // p*12 + g
        int g  = pg % 12;
        int p  = pg / 12;
        int ch0 = 8 * g;                     // 0..88
        const float* src = planes + ((size_t)(p * SC + ch0) * (GRES * GRES)) + xy;
        float v[8];
        #pragma unroll
        for (int i = 0; i < 8; ++i) v[i] = src[(size_t)i * (GRES * GRES)];
        uint32_t w0 = 0, w1 = 0;
        w0 = __builtin_amdgcn_cvt_pk_fp8_f32(v[0], v[1], w0, false);
        w0 = __builtin_amdgcn_cvt_pk_fp8_f32(v[2], v[3], w0, true);
        w1 = __builtin_amdgcn_cvt_pk_fp8_f32(v[4], v[5], w1, false);
        w1 = __builtin_amdgcn_cvt_pk_fp8_f32(v[6], v[7], w1, true);
        uint2 pkt = make_uint2(w0, w1);
        int texel = (p << 14) + xy;          // (p*128+y)*128 + x
        if (g < 8)
            *(uint2*)(A + (size_t)texel * 64 + 8 * g) = pkt;
        else
            *(uint2*)(B + (size_t)texel * 32 + 8 * (g - 8)) = pkt;
    } else if (t < NPLANE_T + NLINE_T) {
        int r = t - NPLANE_T;
        int z  = r & (GRES - 1);
        int pg = r >> 7;
        int g  = pg % 12;
        int p  = pg / 12;
        int ch0 = 8 * g;
        const float* src = lines + ((size_t)(p * SC + ch0) * GRES) + z;
        float v[8];
        #pragma unroll
        for (int i = 0; i < 8; ++i) v[i] = src[(size_t)i * GRES];
        uint32_t w0 = 0, w1 = 0;
        w0 = __builtin_amdgcn_cvt_pk_fp8_f32(v[0], v[1], w0, false);
        w0 = __builtin_amdgcn_cvt_pk_fp8_f32(v[2], v[3], w0, true);
        w1 = __builtin_amdgcn_cvt_pk_fp8_f32(v[4], v[5], w1, false);
        w1 = __builtin_amdgcn_cvt_pk_fp8_f32(v[6], v[7], w1, true);
        *(uint2*)(L + (size_t)(p * GRES + z) * 128 + 8 * g) = make_uint2(w0, w1);
    }
}

__device__ __forceinline__ void axis_setup(float xnv, int& i0, int& i1, float& w)
{
    float f = (xnv + 1.0f) * 0.5f * (float)(GRES - 1);
    f = fminf(fmaxf(f, 0.0f), (float)(GRES - 1));
    float ff = floorf(f);
    i0 = (int)ff;
    i1 = min(i0 + 1, GRES - 1);
    w  = f - ff;
}

// One 32-bit word = 4 fp8 channels of 4 corners + 2 line taps -> 2 packed accs.
__device__ __forceinline__ void word_fma(
    uint32_t wa0, uint32_t wa1, uint32_t wa2, uint32_t wa3,
    uint32_t wl0, uint32_t wl1,
    v2f w0v, v2f w1v, v2f w2v, v2f w3v, v2f uzv, v2f wzv,
    v2f& accE, v2f& accO)
{
    v2f pv = cvt2<false>(wa0) * w0v;
    pv = cvt2<false>(wa1) * w1v + pv;
    pv = cvt2<false>(wa2) * w2v + pv;
    pv = cvt2<false>(wa3) * w3v + pv;
    v2f lv = cvt2<false>(wl1) * wzv;
    lv = cvt2<false>(wl0) * uzv + lv;
    accE = pv * lv + accE;
    v2f pu = cvt2<true>(wa0) * w0v;
    pu = cvt2<true>(wa1) * w1v + pu;
    pu = cvt2<true>(wa2) * w2v + pu;
    pu = cvt2<true>(wa3) * w3v + pu;
    v2f lu = cvt2<true>(wl1) * wzv;
    lu = cvt2<true>(wl0) * uzv + lu;
    accO = pu * lu + accO;
}

// ---------------------------------------------------------------------------
// Main kernel: TWO lanes per point. Lane h owns channels 32h..32h+32 of A
// (s-blocks 2h, 2h+1; two uint4 per corner) and 16 channels of B (s-block
// 4+h; one uint4 per corner). All loads are full 16 B. Reduce = 3 shfl_xor.
// ---------------------------------------------------------------------------
__global__ __launch_bounds__(256) void bwcast_d2(
    const float* __restrict__ xyz, const float* __restrict__ vdirs,
    const uint8_t* __restrict__ A, const uint8_t* __restrict__ B,
    const uint8_t* __restrict__ L, const float* __restrict__ aabb,
    float* __restrict__ out, int N)
{
    int t = blockIdx.x * 256 + threadIdx.x;
    int n = t >> 1;          // point index
    int h = t & 1;           // sub-lane within point
    if (n >= N) return;

    float px = xyz[3 * n + 0], py = xyz[3 * n + 1], pz = xyz[3 * n + 2];
    float xn[3];
    xn[0] = (px - aabb[0]) * (2.0f / (aabb[3] - aabb[0])) - 1.0f;
    xn[1] = (py - aabb[1]) * (2.0f / (aabb[4] - aabb[1])) - 1.0f;
    xn[2] = (pz - aabb[2]) * (2.0f / (aabb[5] - aabb[2])) - 1.0f;

    const uint32_t a32 = (uint32_t)h * 32u;
    const uint32_t b16 = (uint32_t)h * 16u;

    v2f acA0E = (v2f)(0.f), acA0O = (v2f)(0.f);   // s = 2h
    v2f acA1E = (v2f)(0.f), acA1O = (v2f)(0.f);   // s = 2h+1
    v2f acBE  = (v2f)(0.f), acBO  = (v2f)(0.f);   // s = 4+h

    #pragma unroll
    for (int p = 0; p < 3; ++p) {
        constexpr int M0[3] = {0, 0, 1};
        constexpr int M1[3] = {1, 2, 2};
        constexpr int MV[3] = {2, 1, 0};
        int x0, x1, y0, y1, z0, z1;
        float wx, wy, wz;
        axis_setup(xn[M0[p]], x0, x1, wx);
        axis_setup(xn[M1[p]], y0, y1, wy);
        axis_setup(xn[MV[p]], z0, z1, wz);
        uint32_t tex[4];
        tex[0] = (uint32_t)((p * GRES + y0) * GRES + x0);
        tex[1] = (uint32_t)((p * GRES + y0) * GRES + x1);
        tex[2] = (uint32_t)((p * GRES + y1) * GRES + x0);
        tex[3] = (uint32_t)((p * GRES + y1) * GRES + x1);
        uint32_t r0 = (uint32_t)(p * GRES + z0) * 128u;
        uint32_t r1 = (uint32_t)(p * GRES + z1) * 128u;

        // ---- issue this mode's 18 x 16 B loads ----
        uint4 a0[4], a1[4], b4[4];
        #pragma unroll
        for (int c = 0; c < 4; ++c) {
            const uint8_t* ab = A + (size_t)tex[c] * 64u + a32;
            a0[c] = *(const uint4*)(ab);
            a1[c] = *(const uint4*)(ab + 16);
            b4[c] = *(const uint4*)(B + (size_t)tex[c] * 32u + b16);
        }
        uint4 l0A0 = *(const uint4*)(L + r0 + a32);
        uint4 l0A1 = *(const uint4*)(L + r0 + a32 + 16);
        uint4 l0B  = *(const uint4*)(L + r0 + 64u + b16);
        uint4 l1A0 = *(const uint4*)(L + r1 + a32);
        uint4 l1A1 = *(const uint4*)(L + r1 + a32 + 16);
        uint4 l1B  = *(const uint4*)(L + r1 + 64u + b16);

        v2f w0v = (v2f)((1.f - wx) * (1.f - wy));
        v2f w1v = (v2f)(wx * (1.f - wy));
        v2f w2v = (v2f)((1.f - wx) * wy);
        v2f w3v = (v2f)(wx * wy);
        v2f uzv = (v2f)(1.f - wz);
        v2f wzv = (v2f)(wz);

        #pragma unroll
        for (int w = 0; w < 4; ++w)
            word_fma(u4w(a0[0], w), u4w(a0[1], w), u4w(a0[2], w), u4w(a0[3], w),
                     u4w(l0A0, w), u4w(l1A0, w),
                     w0v, w1v, w2v, w3v, uzv, wzv, acA0E, acA0O);
        #pragma unroll
        for (int w = 0; w < 4; ++w)
            word_fma(u4w(a1[0], w), u4w(a1[1], w), u4w(a1[2], w), u4w(a1[3], w),
                     u4w(l0A1, w), u4w(l1A1, w),
                     w0v, w1v, w2v, w3v, uzv, wzv, acA1E, acA1O);
        #pragma unroll
        for (int w = 0; w < 4; ++w)
            word_fma(u4w(b4[0], w), u4w(b4[1], w), u4w(b4[2], w), u4w(b4[3], w),
                     u4w(l0B, w), u4w(l1B, w),
                     w0v, w1v, w2v, w3v, uzv, wzv, acBE, acBO);
    }

    v2f sA0 = acA0E + acA0O;
    v2f sA1 = acA1E + acA1O;
    v2f sB  = acBE + acBO;
    float pA0 = sA0[0] + sA0[1];   // full bw of s = 2h
    float pA1 = sA1[0] + sA1[1];   // full bw of s = 2h+1
    float pB  = sB[0] + sB[1];     // full bw of s = 4+h

    // ---- exchange with partner lane ----
    float oA0 = __shfl_xor(pA0, 1);
    float oA1 = __shfl_xor(pA1, 1);
    float oB  = __shfl_xor(pB, 1);
    float bw[6];
    bw[0] = h ? oA0 : pA0;
    bw[1] = h ? oA1 : pA1;
    bw[2] = h ? pA0 : oA0;
    bw[3] = h ? pA1 : oA1;
    bw[4] = h ? oB  : pB;
    bw[5] = h ? pB  : oB;

    // ---- Rodrigues / screw transform (both lanes redundantly) ----
    float wxr = bw[0], wyr = bw[1], wzr = bw[2];
    float dotw = wxr * wxr + wyr * wyr + wzr * wzr;
    float theta = sqrtf(fmaxf(dotw, 1e-6f));
    float it = 1.0f / theta;
    float ux = wxr * it, uy = wyr * it, un = wzr * it;
    float vx = bw[3] * it, vy = bw[4] * it, vz = bw[5] * it;
    float st = __sinf(theta);
    float ct = __cosf(theta);
    float q   = ux * ux + uy * uy + un * un;   // == 1 unless theta clipped
    float omc = 1.0f - ct;
    float ra = 1.0f - omc * q;                 // skew(u)^2 = uu^T - q I
    float R00 = ra + omc * ux * ux;
    float R01 = omc * ux * uy - st * un;
    float R02 = omc * ux * un + st * uy;
    float R10 = omc * uy * ux + st * un;
    float R11 = ra + omc * uy * uy;
    float R12 = omc * uy * un - st * ux;
    float R20 = omc * un * ux - st * uy;
    float R21 = omc * un * uy + st * ux;
    float R22 = ra + omc * un * un;
    float tms = theta - st;
    float pa  = theta - tms * q;
    float P00 = pa + tms * ux * ux;
    float P01 = tms * ux * uy - omc * un;
    float P02 = tms * ux * un + omc * uy;
    float P10 = tms * uy * ux + omc * un;
    float P11 = pa + tms * uy * uy;
    float P12 = tms * uy * un - omc * ux;
    float P20 = tms * un * ux - omc * uy;
    float P21 = tms * un * uy + omc * ux;
    float P22 = pa + tms * un * un;

    if (h == 0) {
        float tx = P00 * vx + P01 * vy + P02 * vz;
        float ty = P10 * vx + P11 * vy + P12 * vz;
        float tz = P20 * vx + P21 * vy + P22 * vz;
        out[3 * n + 0] = R00 * px + R01 * py + R02 * pz + tx;
        out[3 * n + 1] = R10 * px + R11 * py + R12 * pz + ty;
        out[3 * n + 2] = R20 * px + R21 * py + R22 * pz + tz;
    } else {
        float dx = vdirs[3 * n + 0], dy = vdirs[3 * n + 1], dz = vdirs[3 * n + 2];
        size_t off = (size_t)3 * N;
        out[off + 3 * n + 0] = R00 * dx + R01 * dy + R02 * dz;
        out[off + 3 * n + 1] = R10 * dx + R11 * dy + R12 * dz;
        out[off + 3 * n + 2] = R20 * dx + R21 * dy + R22 * dz;
    }
}

// ---------------------------------------------------------------------------
// Fallback: original layouts, f32 (only if d_ws too small).
// ---------------------------------------------------------------------------
__global__ __launch_bounds__(256) void bwcast_direct(
    const float* __restrict__ xyz, const float* __restrict__ vdirs,
    const float* __restrict__ PL, const float* __restrict__ LN,
    const float* __restrict__ aabb, float* __restrict__ out, int N)
{
    int n = blockIdx.x * 256 + threadIdx.x;
    if (n >= N) return;

    float px = xyz[3 * n + 0], py = xyz[3 * n + 1], pz = xyz[3 * n + 2];
    float xn[3];
    xn[0] = (px - aabb[0]) * (2.0f / (aabb[3] - aabb[0])) - 1.0f;
    xn[1] = (py - aabb[1]) * (2.0f / (aabb[4] - aabb[1])) - 1.0f;
    xn[2] = (pz - aabb[2]) * (2.0f / (aabb[5] - aabb[2])) - 1.0f;

    float bw[6] = {0.f, 0.f, 0.f, 0.f, 0.f, 0.f};

    #pragma unroll
    for (int p = 0; p < 3; ++p) {
        constexpr int M0[3] = {0, 0, 1};
        constexpr int M1[3] = {1, 2, 2};
        constexpr int MV[3] = {2, 1, 0};
        int x0, x1, y0, y1, z0, z1;
        float wx, wy, wz;
        axis_setup(xn[M0[p]], x0, x1, wx);
        axis_setup(xn[M1[p]], y0, y1, wy);
        axis_setup(xn[MV[p]], z0, z1, wz);
        float w00 = (1.f - wx) * (1.f - wy);
        float w01 = wx * (1.f - wy);
        float w10 = (1.f - wx) * wy;
        float w11 = wx * wy;
        float uz = 1.f - wz;
        #pragma unroll
        for (int s = 0; s < 6; ++s) {
            float acc = bw[s];
            for (int c = 0; c < 16; ++c) {
                int sc = s * 16 + c;
                const float* pb = PL + (size_t)(p * SC + sc) * (GRES * GRES);
                float f00 = pb[y0 * GRES + x0];
                float f01 = pb[y0 * GRES + x1];
                float f10 = pb[y1 * GRES + x0];
                float f11 = pb[y1 * GRES + x1];
                const float* lb = LN + (size_t)(p * SC + sc) * GRES;
                float lv = fmaf(lb[z0], uz, lb[z1] * wz);
                float pv = fmaf(f00, w00, fmaf(f01, w01, fmaf(f10, w10, f11 * w11)));
                acc = fmaf(pv, lv, acc);
            }
            bw[s] = acc;
        }
    }

    float wxr = bw[0], wyr = bw[1], wzr = bw[2];
    float dotw = wxr * wxr + wyr * wyr + wzr * wzr;
    float theta = sqrtf(fmaxf(dotw, 1e-6f));
    float it = 1.0f / theta;
    float ux = wxr * it, uy = wyr * it, un = wzr * it;
    float vx = bw[3] * it, vy = bw[4] * it, vz = bw[5] * it;
    float st, ct;
    sincosf(theta, &st, &ct);
    float q   = ux * ux + uy * uy + un * un;
    float omc = 1.0f - ct;
    float ra = 1.0f - omc * q;
    float R00 = ra + omc * ux * ux;
    float R01 = omc * ux * uy - st * un;
    float R02 = omc * ux * un + st * uy;
    float R10 = omc * uy * ux + st * un;
    float R11 = ra + omc * uy * uy;
    float R12 = omc * uy * un - st * ux;
    float R20 = omc * un * ux - st * uy;
    float R21 = omc * un * uy + st * ux;
    float R22 = ra + omc * un * un;
    float tms = theta - st;
    float pa  = theta - tms * q;
    float P00 = pa + tms * ux * ux;
    float P01 = tms * ux * uy - omc * un;
    float P02 = tms * ux * un + omc * uy;
    float P10 = tms * uy * ux + omc * un;
    float P11 = pa + tms * uy * uy;
    float P12 = tms * uy * un - omc * ux;
    float P20 = tms * un * ux - omc * uy;
    float P21 = tms * un * uy + omc * ux;
    float P22 = pa + tms * un * un;

    float tx = P00 * vx + P01 * vy + P02 * vz;
    float ty = P10 * vx + P11 * vy + P12 * vz;
    float tz = P20 * vx + P21 * vy + P22 * vz;

    out[3 * n + 0] = R00 * px + R01 * py + R02 * pz + tx;
    out[3 * n + 1] = R10 * px + R11 * py + R12 * pz + ty;
    out[3 * n + 2] = R20 * px + R21 * py + R22 * pz + tz;

    float dx = vdirs[3 * n + 0], dy = vdirs[3 * n + 1], dz = vdirs[3 * n + 2];
    size_t off = (size_t)3 * N;
    out[off + 3 * n + 0] = R00 * dx + R01 * dy + R02 * dz;
    out[off + 3 * n + 1] = R10 * dx + R11 * dy + R12 * dz;
    out[off + 3 * n + 2] = R20 * dx + R21 * dy + R22 * dz;
}

extern "C" void kernel_launch(void* const* d_in, const int* in_sizes, int n_in,
                              void* d_out, int out_size, void* d_ws, size_t ws_size,
                              hipStream_t stream)
{
    const float* xyz    = (const float*)d_in[0];
    const float* vd     = (const float*)d_in[1];
    // d_in[2] = transforms (unused), d_in[3] = ray_valid (unused)
    const float* planes = (const float*)d_in[4];
    const float* lines  = (const float*)d_in[5];
    const float* aabb   = (const float*)d_in[6];
    float* out = (float*)d_out;

    int N = in_sizes[0] / 3;   // 524288

    size_t szA = (size_t)3 * GRES * GRES * 64;   // 3.15 MB
    size_t szB = (size_t)3 * GRES * GRES * 32;   // 1.57 MB
    size_t szL = (size_t)3 * GRES * 128;         // 49 KB

    if (ws_size >= szA + szB + szL) {
        uint8_t* A = (uint8_t*)d_ws;
        uint8_t* Bp = A + szA;
        uint8_t* L = Bp + szB;
        int tp_threads = NPLANE_T + NLINE_T;
        tp_split<<<(tp_threads + 255) / 256, 256, 0, stream>>>(planes, lines, A, Bp, L);
        int threads = N * 2;
        bwcast_d2<<<(threads + 255) / 256, 256, 0, stream>>>(
            xyz, vd, A, Bp, L, aabb, out, N);
    } else {
        bwcast_direct<<<(N + 255) / 256, 256, 0, stream>>>(xyz, vd, planes, lines, aabb, out, N);
    }
}

// Round 14
// 147.217 us; speedup vs baseline: 1.2330x; 1.2330x over previous
//
#include <hip/hip_runtime.h>
#include <cstdint>
#include <cstddef>

#define GRES 128   // grid resolution (H = W = L)
#define SC   96    // S*C = 6*16 channels

typedef float v2f __attribute__((ext_vector_type(2)));

// Word-select of cvt_pk_f32_fp8 must be a compile-time constant at sema time.
template<bool HI>
__device__ __forceinline__ v2f cvt2(uint32_t q)
{
    return __builtin_amdgcn_cvt_pk_f32_fp8(q, HI);
}

__device__ __forceinline__ uint32_t u4w(const uint4& q, int c)
{
    return c == 0 ? q.x : c == 1 ? q.y : c == 2 ? q.z : q.w;
}

// ---------------------------------------------------------------------------
// LDS-free transpose/quantize (unchanged — measured cheap).
//  A[texel][ch 0..64)   : 64 B records (fp8)
//  B[texel][ch 64..96)  : 32 B records (fp8)
//  L[(p,z)][ch 0..96)   : 128 B padded records (fp8 lines)
// ---------------------------------------------------------------------------
#define NPLANE_T (3 * 12 * GRES * GRES)   // 589824
#define NLINE_T  (3 * 12 * GRES)          // 4608

__global__ __launch_bounds__(256) void tp_split(const float* __restrict__ planes,
                                                const float* __restrict__ lines,
                                                uint8_t* __restrict__ A,
                                                uint8_t* __restrict__ B,
                                                uint8_t* __restrict__ L)
{
    int t = blockIdx.x * 256 + threadIdx.x;
    if (t < NPLANE_T) {
        int xy = t & (GRES * GRES - 1);      // y*128 + x
        int pg = t >> 14;                    // p*12 + g
        int g  = pg % 12;
        int p  = pg / 12;
        int ch0 = 8 * g;                     // 0..88
        const float* src = planes + ((size_t)(p * SC + ch0) * (GRES * GRES)) + xy;
        float v[8];
        #pragma unroll
        for (int i = 0; i < 8; ++i) v[i] = src[(size_t)i * (GRES * GRES)];
        uint32_t w0 = 0, w1 = 0;
        w0 = __builtin_amdgcn_cvt_pk_fp8_f32(v[0], v[1], w0, false);
        w0 = __builtin_amdgcn_cvt_pk_fp8_f32(v[2], v[3], w0, true);
        w1 = __builtin_amdgcn_cvt_pk_fp8_f32(v[4], v[5], w1, false);
        w1 = __builtin_amdgcn_cvt_pk_fp8_f32(v[6], v[7], w1, true);
        uint2 pkt = make_uint2(w0, w1);
        int texel = (p << 14) + xy;          // (p*128+y)*128 + x
        if (g < 8)
            *(uint2*)(A + (size_t)texel * 64 + 8 * g) = pkt;
        else
            *(uint2*)(B + (size_t)texel * 32 + 8 * (g - 8)) = pkt;
    } else if (t < NPLANE_T + NLINE_T) {
        int r = t - NPLANE_T;
        int z  = r & (GRES - 1);
        int pg = r >> 7;
        int g  = pg % 12;
        int p  = pg / 12;
        int ch0 = 8 * g;
        const float* src = lines + ((size_t)(p * SC + ch0) * GRES) + z;
        float v[8];
        #pragma unroll
        for (int i = 0; i < 8; ++i) v[i] = src[(size_t)i * GRES];
        uint32_t w0 = 0, w1 = 0;
        w0 = __builtin_amdgcn_cvt_pk_fp8_f32(v[0], v[1], w0, false);
        w0 = __builtin_amdgcn_cvt_pk_fp8_f32(v[2], v[3], w0, true);
        w1 = __builtin_amdgcn_cvt_pk_fp8_f32(v[4], v[5], w1, false);
        w1 = __builtin_amdgcn_cvt_pk_fp8_f32(v[6], v[7], w1, true);
        *(uint2*)(L + (size_t)(p * GRES + z) * 128 + 8 * g) = make_uint2(w0, w1);
    }
}

__device__ __forceinline__ void axis_setup(float xnv, int& i0, int& i1, float& w)
{
    float f = (xnv + 1.0f) * 0.5f * (float)(GRES - 1);
    f = fminf(fmaxf(f, 0.0f), (float)(GRES - 1));
    float ff = floorf(f);
    i0 = (int)ff;
    i1 = min(i0 + 1, GRES - 1);
    w  = f - ff;
}

// ---------------------------------------------------------------------------
// Main kernel: FOUR lanes per point (round-11 winner) + fenced 2-deep mode
// pipeline. Lane l owns s-block l (16 ch via uint4 from A per corner) plus
// half of s-block 4+(l>>1) (8 ch via uint2 from B). sched_barrier(0) after
// each issue block stops the compiler from sinking loads to their consumers
// (which defeated the round-7/10 pipeline attempt, VGPR stuck at 60).
// ---------------------------------------------------------------------------
__global__ __launch_bounds__(256) void bwcast_s4p(
    const float* __restrict__ xyz, const float* __restrict__ vdirs,
    const uint8_t* __restrict__ A, const uint8_t* __restrict__ B,
    const uint8_t* __restrict__ L, const float* __restrict__ aabb,
    float* __restrict__ out, int N)
{
    int t = blockIdx.x * 256 + threadIdx.x;
    int n = t >> 2;          // point index
    int l = t & 3;           // sub-lane within point
    if (n >= N) return;
    int lane = threadIdx.x & 63;

    float px = xyz[3 * n + 0], py = xyz[3 * n + 1], pz = xyz[3 * n + 2];
    float xn[3];
    xn[0] = (px - aabb[0]) * (2.0f / (aabb[3] - aabb[0])) - 1.0f;
    xn[1] = (py - aabb[1]) * (2.0f / (aabb[4] - aabb[1])) - 1.0f;
    xn[2] = (pz - aabb[2]) * (2.0f / (aabb[5] - aabb[2])) - 1.0f;

    uint32_t aoff[3][4], boff[3][4];   // byte offsets into A / B
    uint32_t lo4[3][2], lo2[3][2];     // byte offsets into L
    float W[3][4], UZ[3], WZ[3];

    #pragma unroll
    for (int p = 0; p < 3; ++p) {
        constexpr int M0[3] = {0, 0, 1};
        constexpr int M1[3] = {1, 2, 2};
        constexpr int MV[3] = {2, 1, 0};
        int x0, x1, y0, y1, z0, z1;
        float wx, wy, wz;
        axis_setup(xn[M0[p]], x0, x1, wx);
        axis_setup(xn[M1[p]], y0, y1, wy);
        axis_setup(xn[MV[p]], z0, z1, wz);
        uint32_t t00 = (uint32_t)((p * GRES + y0) * GRES + x0);
        uint32_t t01 = (uint32_t)((p * GRES + y0) * GRES + x1);
        uint32_t t10 = (uint32_t)((p * GRES + y1) * GRES + x0);
        uint32_t t11 = (uint32_t)((p * GRES + y1) * GRES + x1);
        uint32_t a16 = (uint32_t)l * 16u, b8 = (uint32_t)l * 8u;
        aoff[p][0] = t00 * 64u + a16;  boff[p][0] = t00 * 32u + b8;
        aoff[p][1] = t01 * 64u + a16;  boff[p][1] = t01 * 32u + b8;
        aoff[p][2] = t10 * 64u + a16;  boff[p][2] = t10 * 32u + b8;
        aoff[p][3] = t11 * 64u + a16;  boff[p][3] = t11 * 32u + b8;
        uint32_t r0 = (uint32_t)(p * GRES + z0) * 128u;
        uint32_t r1 = (uint32_t)(p * GRES + z1) * 128u;
        lo4[p][0] = r0 + a16;          lo2[p][0] = r0 + 64u + b8;
        lo4[p][1] = r1 + a16;          lo2[p][1] = r1 + 64u + b8;
        W[p][0] = (1.f - wx) * (1.f - wy);
        W[p][1] = wx * (1.f - wy);
        W[p][2] = (1.f - wx) * wy;
        W[p][3] = wx * wy;
        UZ[p] = 1.f - wz;
        WZ[p] = wz;
    }

    v2f aLE = (v2f)(0.f), aLO = (v2f)(0.f);   // lo (16-ch) even/odd pair accs
    v2f aHE = (v2f)(0.f), aHO = (v2f)(0.f);   // hi (8-ch) even/odd pair accs

    auto issue = [&](int p, uint4 (&a4)[4], uint2 (&b2)[4],
                     uint4 (&l4)[2], uint2 (&l2)[2]) {
        #pragma unroll
        for (int c = 0; c < 4; ++c) {
            a4[c] = *(const uint4*)(A + aoff[p][c]);
            b2[c] = *(const uint2*)(B + boff[p][c]);
        }
        #pragma unroll
        for (int d = 0; d < 2; ++d) {
            l4[d] = *(const uint4*)(L + lo4[p][d]);
            l2[d] = *(const uint2*)(L + lo2[p][d]);
        }
    };

    auto consume = [&](int p, const uint4 (&a4)[4], const uint2 (&b2)[4],
                       const uint4 (&l4)[2], const uint2 (&l2)[2]) {
        v2f w0v = (v2f)(W[p][0]);
        v2f w1v = (v2f)(W[p][1]);
        v2f w2v = (v2f)(W[p][2]);
        v2f w3v = (v2f)(W[p][3]);
        v2f uzv = (v2f)(UZ[p]);
        v2f wzv = (v2f)(WZ[p]);

        #pragma unroll
        for (int k = 0; k < 4; ++k) {
            uint32_t wa0 = u4w(a4[0], k), wa1 = u4w(a4[1], k);
            uint32_t wa2 = u4w(a4[2], k), wa3 = u4w(a4[3], k);
            uint32_t wl0 = u4w(l4[0], k), wl1 = u4w(l4[1], k);
            v2f pv = cvt2<false>(wa0) * w0v;
            pv = cvt2<false>(wa1) * w1v + pv;
            pv = cvt2<false>(wa2) * w2v + pv;
            pv = cvt2<false>(wa3) * w3v + pv;
            v2f lv = cvt2<false>(wl1) * wzv;
            lv = cvt2<false>(wl0) * uzv + lv;
            aLE = pv * lv + aLE;
            v2f pu = cvt2<true>(wa0) * w0v;
            pu = cvt2<true>(wa1) * w1v + pu;
            pu = cvt2<true>(wa2) * w2v + pu;
            pu = cvt2<true>(wa3) * w3v + pu;
            v2f lu = cvt2<true>(wl1) * wzv;
            lu = cvt2<true>(wl0) * uzv + lu;
            aLO = pu * lu + aLO;
        }
        #pragma unroll
        for (int k = 0; k < 2; ++k) {
            uint32_t wb0 = k ? b2[0].y : b2[0].x;
            uint32_t wb1 = k ? b2[1].y : b2[1].x;
            uint32_t wb2 = k ? b2[2].y : b2[2].x;
            uint32_t wb3 = k ? b2[3].y : b2[3].x;
            uint32_t wl0 = k ? l2[0].y : l2[0].x;
            uint32_t wl1 = k ? l2[1].y : l2[1].x;
            v2f pv = cvt2<false>(wb0) * w0v;
            pv = cvt2<false>(wb1) * w1v + pv;
            pv = cvt2<false>(wb2) * w2v + pv;
            pv = cvt2<false>(wb3) * w3v + pv;
            v2f lv = cvt2<false>(wl1) * wzv;
            lv = cvt2<false>(wl0) * uzv + lv;
            aHE = pv * lv + aHE;
            v2f pu = cvt2<true>(wb0) * w0v;
            pu = cvt2<true>(wb1) * w1v + pu;
            pu = cvt2<true>(wb2) * w2v + pu;
            pu = cvt2<true>(wb3) * w3v + pu;
            v2f lu = cvt2<true>(wl1) * wzv;
            lu = cvt2<true>(wl0) * uzv + lu;
            aHO = pu * lu + aHO;
        }
    };

    // Fenced 2-deep pipeline over modes: X=mode0, Y=mode1; mode2 reuses X.
    uint4 a4X[4]; uint2 b2X[4]; uint4 l4X[2]; uint2 l2X[2];
    uint4 a4Y[4]; uint2 b2Y[4]; uint4 l4Y[2]; uint2 l2Y[2];
    issue(0, a4X, b2X, l4X, l2X);
    issue(1, a4Y, b2Y, l4Y, l2Y);
    __builtin_amdgcn_sched_barrier(0);    // loads above may not sink below
    consume(0, a4X, b2X, l4X, l2X);
    issue(2, a4X, b2X, l4X, l2X);
    __builtin_amdgcn_sched_barrier(0);
    consume(1, a4Y, b2Y, l4Y, l2Y);
    consume(2, a4X, b2X, l4X, l2X);

    v2f sl = aLE + aLO;
    float part_lo = sl[0] + sl[1];       // full bw of s = l
    v2f sh = aHE + aHO;
    float part_hi = sh[0] + sh[1];       // half of s = 4 + (l>>1)

    // ---- reduce / broadcast within 4-lane group ----
    int base = lane & ~3;
    float bw[6];
    bw[0] = __shfl(part_lo, base + 0);
    bw[1] = __shfl(part_lo, base + 1);
    bw[2] = __shfl(part_lo, base + 2);
    bw[3] = __shfl(part_lo, base + 3);
    float ph2 = part_hi + __shfl_xor(part_hi, 1);
    bw[4] = __shfl(ph2, base + 0);
    bw[5] = __shfl(ph2, base + 2);

    // ---- Rodrigues / screw transform (all 4 lanes redundantly) ----
    float wxr = bw[0], wyr = bw[1], wzr = bw[2];
    float dotw = wxr * wxr + wyr * wyr + wzr * wzr;
    float theta = sqrtf(fmaxf(dotw, 1e-6f));
    float it = 1.0f / theta;
    float ux = wxr * it, uy = wyr * it, un = wzr * it;
    float vx = bw[3] * it, vy = bw[4] * it, vz = bw[5] * it;
    float st = __sinf(theta);
    float ct = __cosf(theta);
    float q   = ux * ux + uy * uy + un * un;   // == 1 unless theta clipped
    float omc = 1.0f - ct;
    float ra = 1.0f - omc * q;                 // skew(u)^2 = uu^T - q I
    float R00 = ra + omc * ux * ux;
    float R01 = omc * ux * uy - st * un;
    float R02 = omc * ux * un + st * uy;
    float R10 = omc * uy * ux + st * un;
    float R11 = ra + omc * uy * uy;
    float R12 = omc * uy * un - st * ux;
    float R20 = omc * un * ux - st * uy;
    float R21 = omc * un * uy + st * ux;
    float R22 = ra + omc * un * un;
    float tms = theta - st;
    float pa  = theta - tms * q;
    float P00 = pa + tms * ux * ux;
    float P01 = tms * ux * uy - omc * un;
    float P02 = tms * ux * un + omc * uy;
    float P10 = tms * uy * ux + omc * un;
    float P11 = pa + tms * uy * uy;
    float P12 = tms * uy * un - omc * ux;
    float P20 = tms * un * ux - omc * uy;
    float P21 = tms * un * uy + omc * ux;
    float P22 = pa + tms * un * un;

    float tx = P00 * vx + P01 * vy + P02 * vz;
    float ty = P10 * vx + P11 * vy + P12 * vz;
    float tz = P20 * vx + P21 * vy + P22 * vz;

    float ox = R00 * px + R01 * py + R02 * pz + tx;
    float oy = R10 * px + R11 * py + R12 * pz + ty;
    float oz = R20 * px + R21 * py + R22 * pz + tz;

    float dx = vdirs[3 * n + 0], dy = vdirs[3 * n + 1], dz = vdirs[3 * n + 2];
    float wvx = R00 * dx + R01 * dy + R02 * dz;
    float wvy = R10 * dx + R11 * dy + R12 * dz;
    float wvz = R20 * dx + R21 * dy + R22 * dz;

    if (l < 3) {
        float o  = (l == 0) ? ox : (l == 1) ? oy : oz;
        float wv = (l == 0) ? wvx : (l == 1) ? wvy : wvz;
        out[3 * n + l] = o;
        out[(size_t)3 * N + 3 * n + l] = wv;
    }
}

// ---------------------------------------------------------------------------
// Fallback: original layouts, f32 (only if d_ws too small).
// ---------------------------------------------------------------------------
__global__ __launch_bounds__(256) void bwcast_direct(
    const float* __restrict__ xyz, const float* __restrict__ vdirs,
    const float* __restrict__ PL, const float* __restrict__ LN,
    const float* __restrict__ aabb, float* __restrict__ out, int N)
{
    int n = blockIdx.x * 256 + threadIdx.x;
    if (n >= N) return;

    float px = xyz[3 * n + 0], py = xyz[3 * n + 1], pz = xyz[3 * n + 2];
    float xn[3];
    xn[0] = (px - aabb[0]) * (2.0f / (aabb[3] - aabb[0])) - 1.0f;
    xn[1] = (py - aabb[1]) * (2.0f / (aabb[4] - aabb[1])) - 1.0f;
    xn[2] = (pz - aabb[2]) * (2.0f / (aabb[5] - aabb[2])) - 1.0f;

    float bw[6] = {0.f, 0.f, 0.f, 0.f, 0.f, 0.f};

    #pragma unroll
    for (int p = 0; p < 3; ++p) {
        constexpr int M0[3] = {0, 0, 1};
        constexpr int M1[3] = {1, 2, 2};
        constexpr int MV[3] = {2, 1, 0};
        int x0, x1, y0, y1, z0, z1;
        float wx, wy, wz;
        axis_setup(xn[M0[p]], x0, x1, wx);
        axis_setup(xn[M1[p]], y0, y1, wy);
        axis_setup(xn[MV[p]], z0, z1, wz);
        float w00 = (1.f - wx) * (1.f - wy);
        float w01 = wx * (1.f - wy);
        float w10 = (1.f - wx) * wy;
        float w11 = wx * wy;
        float uz = 1.f - wz;
        #pragma unroll
        for (int s = 0; s < 6; ++s) {
            float acc = bw[s];
            for (int c = 0; c < 16; ++c) {
                int sc = s * 16 + c;
                const float* pb = PL + (size_t)(p * SC + sc) * (GRES * GRES);
                float f00 = pb[y0 * GRES + x0];
                float f01 = pb[y0 * GRES + x1];
                float f10 = pb[y1 * GRES + x0];
                float f11 = pb[y1 * GRES + x1];
                const float* lb = LN + (size_t)(p * SC + sc) * GRES;
                float lv = fmaf(lb[z0], uz, lb[z1] * wz);
                float pv = fmaf(f00, w00, fmaf(f01, w01, fmaf(f10, w10, f11 * w11)));
                acc = fmaf(pv, lv, acc);
            }
            bw[s] = acc;
        }
    }

    float wxr = bw[0], wyr = bw[1], wzr = bw[2];
    float dotw = wxr * wxr + wyr * wyr + wzr * wzr;
    float theta = sqrtf(fmaxf(dotw, 1e-6f));
    float it = 1.0f / theta;
    float ux = wxr * it, uy = wyr * it, un = wzr * it;
    float vx = bw[3] * it, vy = bw[4] * it, vz = bw[5] * it;
    float st, ct;
    sincosf(theta, &st, &ct);
    float q   = ux * ux + uy * uy + un * un;
    float omc = 1.0f - ct;
    float ra = 1.0f - omc * q;
    float R00 = ra + omc * ux * ux;
    float R01 = omc * ux * uy - st * un;
    float R02 = omc * ux * un + st * uy;
    float R10 = omc * uy * ux + st * un;
    float R11 = ra + omc * uy * uy;
    float R12 = omc * uy * un - st * ux;
    float R20 = omc * un * ux - st * uy;
    float R21 = omc * un * uy + st * ux;
    float R22 = ra + omc * un * un;
    float tms = theta - st;
    float pa  = theta - tms * q;
    float P00 = pa + tms * ux * ux;
    float P01 = tms * ux * uy - omc * un;
    float P02 = tms * ux * un + omc * uy;
    float P10 = tms * uy * ux + omc * un;
    float P11 = pa + tms * uy * uy;
    float P12 = tms * uy * un - omc * ux;
    float P20 = tms * un * ux - omc * uy;
    float P21 = tms * un * uy + omc * ux;
    float P22 = pa + tms * un * un;

    float tx = P00 * vx + P01 * vy + P02 * vz;
    float ty = P10 * vx + P11 * vy + P12 * vz;
    float tz = P20 * vx + P21 * vy + P22 * vz;

    out[3 * n + 0] = R00 * px + R01 * py + R02 * pz + tx;
    out[3 * n + 1] = R10 * px + R11 * py + R12 * pz + ty;
    out[3 * n + 2] = R20 * px + R21 * py + R22 * pz + tz;

    float dx = vdirs[3 * n + 0], dy = vdirs[3 * n + 1], dz = vdirs[3 * n + 2];
    size_t off = (size_t)3 * N;
    out[off + 3 * n + 0] = R00 * dx + R01 * dy + R02 * dz;
    out[off + 3 * n + 1] = R10 * dx + R11 * dy + R12 * dz;
    out[off + 3 * n + 2] = R20 * dx + R21 * dy + R22 * dz;
}

extern "C" void kernel_launch(void* const* d_in, const int* in_sizes, int n_in,
                              void* d_out, int out_size, void* d_ws, size_t ws_size,
                              hipStream_t stream)
{
    const float* xyz    = (const float*)d_in[0];
    const float* vd     = (const float*)d_in[1];
    // d_in[2] = transforms (unused), d_in[3] = ray_valid (unused)
    const float* planes = (const float*)d_in[4];
    const float* lines  = (const float*)d_in[5];
    const float* aabb   = (const float*)d_in[6];
    float* out = (float*)d_out;

    int N = in_sizes[0] / 3;   // 524288

    size_t szA = (size_t)3 * GRES * GRES * 64;   // 3.15 MB
    size_t szB = (size_t)3 * GRES * GRES * 32;   // 1.57 MB
    size_t szL = (size_t)3 * GRES * 128;         // 49 KB

    if (ws_size >= szA + szB + szL) {
        uint8_t* A = (uint8_t*)d_ws;
        uint8_t* Bp = A + szA;
        uint8_t* L = Bp + szB;
        int tp_threads = NPLANE_T + NLINE_T;
        tp_split<<<(tp_threads + 255) / 256, 256, 0, stream>>>(planes, lines, A, Bp, L);
        int threads = N * 4;
        bwcast_s4p<<<(threads + 255) / 256, 256, 0, stream>>>(
            xyz, vd, A, Bp, L, aabb, out, N);
    } else {
        bwcast_direct<<<(N + 255) / 256, 256, 0, stream>>>(xyz, vd, planes, lines, aabb, out, N);
    }
}